// Round 4
// baseline (717.473 us; speedup 1.0000x reference)
//
#include <hip/hip_runtime.h>
#include <hip/hip_bf16.h>
#include <cstdint>

#define HH 128
#define WW 128
#define CC 64
#define BB 16
#define PLANE (HH*WW)
#define TPSTR 16512   // T plane stride: 16384 + 128 floats (512 B pad) breaks
                      // the 64-KB power-of-2 channel/set aliasing in k_mix.

// k_dwsum LDS layout (two-pass xbuf -> 39552 B -> 4 blocks/CU).
//   xs   [84][52] f32  U row-major, rows -10..73, cols -10..41
//   xsTh [36][72] bf16 U col-major, cols -2..33, rows -2..65
//   h7T  [32][88] bf16 rows -3..66 (70 used)
//   union { xbuf [44][60] f32 (phase A, two passes: raw rows 0..43 / 42..85)
//         | h11T [32][88] bf16 ; h21T [32][88] bf16 }
#define XS_STR    52
#define XRAW_STR  60
#define XSTH_H    8736    // half-index of xsTh   (= 4368 floats * 2)
#define H7_H      11328   // half-index of h7T    (= 5664 floats * 2)
#define UNION_F   7072    // float-index of xbuf
#define H11_H     14144   // half-index of h11T   (inside union)
#define H21_H     16960   // half-index of h21T   (inside union)
#define SMEM_FLOATS 9888  // 39552 B -> 4 blocks/CU

__device__ __forceinline__ float lo16(unsigned int u) {
  return __uint_as_float(u << 16);
}
__device__ __forceinline__ float hi16(unsigned int u) {
  return __uint_as_float(u & 0xffff0000u);
}

__device__ __forceinline__ void a2_store(float* sm, __hip_bfloat16* xsTh,
                                         int rr, int jj, const float uq[4]) {
  *(float4*)(sm + rr * XS_STR + jj * 4) =
      make_float4(uq[0], uq[1], uq[2], uq[3]);
  int rt = rr - 8;                       // xsTh row (tile row -2..65)
  if ((unsigned)rt < 68u) {
    #pragma unroll
    for (int q = 0; q < 4; ++q) {
      int ct = jj * 4 + q - 8;           // xsTh col (tile col -2..33)
      if ((unsigned)ct < 36u)
        xsTh[ct * 72 + rt] = __float2bfloat16(uq[q]);
    }
  }
}

// Fast path: no border masking (valid only for interior items; border items
// get overwritten by the fixup pass). Factored column sums/maxes.
__device__ __forceinline__ void a2_item_fast(float* sm, __hip_bfloat16* xsTh,
                                             const float* xbuf, int rg,
                                             int jj, int roff) {
  int rr0 = rg * 3;
  const float* rp = xbuf + (rr0 - roff) * XRAW_STR + jj * 4;
  float w[5][8];
  #pragma unroll
  for (int k = 0; k < 5; ++k) {
    float4 a = *(const float4*)(rp + k * XRAW_STR);
    float4 b = *(const float4*)(rp + k * XRAW_STR + 4);
    w[k][0] = a.x; w[k][1] = a.y; w[k][2] = a.z; w[k][3] = a.w;
    w[k][4] = b.x; w[k][5] = b.y; w[k][6] = b.z; w[k][7] = b.w;
  }
  float cs[3][7], cm[3][7];
  #pragma unroll
  for (int p = 1; p <= 6; ++p) {
    float a0 = w[0][p], a1 = w[1][p], a2 = w[2][p], a3 = w[3][p],
          a4 = w[4][p];
    float s12 = a1 + a2;
    cs[0][p] = a0 + s12;
    cs[1][p] = s12 + a3;
    float s34 = a3 + a4;
    cs[2][p] = a2 + s34;
    float m12 = fmaxf(a1, a2);
    cm[0][p] = fmaxf(a0, m12);
    cm[1][p] = fmaxf(m12, a3);
    float m34 = fmaxf(a3, a4);
    cm[2][p] = fmaxf(a2, m34);
  }
  #pragma unroll
  for (int k = 0; k < 3; ++k) {
    float t23 = cs[k][2] + cs[k][3];
    float t45 = cs[k][4] + cs[k][5];
    float n23 = fmaxf(cm[k][2], cm[k][3]);
    float n45 = fmaxf(cm[k][4], cm[k][5]);
    float uq[4];
    uq[0] = w[k + 1][2] + (cs[k][1] + t23) * (1.f / 9.f) +
            fmaxf(cm[k][1], n23);
    uq[1] = w[k + 1][3] + (t23 + cs[k][4]) * (1.f / 9.f) +
            fmaxf(n23, cm[k][4]);
    uq[2] = w[k + 1][4] + (cs[k][3] + t45) * (1.f / 9.f) +
            fmaxf(cm[k][3], n45);
    uq[3] = w[k + 1][5] + (t45 + cs[k][6]) * (1.f / 9.f) +
            fmaxf(n45, cm[k][6]);
    a2_store(sm, xsTh, rr0 + k, jj, uq);
  }
}

// Slow path: verbatim original masked math (exact at borders).
__device__ __forceinline__ void a2_item_slow(float* sm, __hip_bfloat16* xsTh,
                                             const float* xbuf, int tR0,
                                             int tC0, int rg, int jj,
                                             int roff) {
  int rr0 = rg * 3;
  const float* rp = xbuf + (rr0 - roff) * XRAW_STR + jj * 4;
  float w[5][8];
  #pragma unroll
  for (int k = 0; k < 5; ++k) {
    float4 a = *(const float4*)(rp + k * XRAW_STR);
    float4 b = *(const float4*)(rp + k * XRAW_STR + 4);
    w[k][0] = a.x; w[k][1] = a.y; w[k][2] = a.z; w[k][3] = a.w;
    w[k][4] = b.x; w[k][5] = b.y; w[k][6] = b.z; w[k][7] = b.w;
  }
  int gc0 = tC0 + jj * 4 - 12;
  bool cv[7];
  #pragma unroll
  for (int p = 1; p <= 6; ++p) cv[p] = (unsigned)(gc0 + p) < 128u;

  #pragma unroll
  for (int k = 0; k < 3; ++k) {
    int rr = rr0 + k;
    int gr = tR0 + rr - 10;
    bool rv0 = (unsigned)(gr - 1) < 128u;
    bool rv1 = (unsigned)(gr) < 128u;
    bool rv2 = (unsigned)(gr + 1) < 128u;
    float M0[7], M1[7], M2[7];
    #pragma unroll
    for (int p = 1; p <= 6; ++p) {
      M0[p] = (rv0 && cv[p]) ? w[k][p] : -3.402823466e38f;
      M1[p] = (rv1 && cv[p]) ? w[k + 1][p] : -3.402823466e38f;
      M2[p] = (rv2 && cv[p]) ? w[k + 2][p] : -3.402823466e38f;
    }
    float uq[4];
    #pragma unroll
    for (int q = 0; q < 4; ++q) {
      float s = w[k][q + 1] + w[k][q + 2] + w[k][q + 3] + w[k + 1][q + 1] +
                w[k + 1][q + 2] + w[k + 1][q + 3] + w[k + 2][q + 1] +
                w[k + 2][q + 2] + w[k + 2][q + 3];
      float m = fmaxf(
          fmaxf(fmaxf(M0[q + 1], M0[q + 2]), fmaxf(M0[q + 3], M1[q + 1])),
          fmaxf(fmaxf(M1[q + 2], M1[q + 3]),
                fmaxf(fmaxf(M2[q + 1], M2[q + 2]), M2[q + 3])));
      float val = w[k + 1][q + 2] + s * (1.f / 9.f) + m;
      bool vo = rv1 && ((unsigned)(gc0 + q + 2) < 128u);
      uq[q] = vo ? val : 0.f;
    }
    a2_store(sm, xsTh, rr, jj, uq);
  }
}

__global__ __launch_bounds__(256, 4) void k_dwsum(
    const float* __restrict__ x, float* __restrict__ T,
    const float* __restrict__ w55, const float* __restrict__ b55,
    const float* __restrict__ w17_0, const float* __restrict__ b17_0,
    const float* __restrict__ w17_1, const float* __restrict__ b17_1,
    const float* __restrict__ w111_0, const float* __restrict__ b111_0,
    const float* __restrict__ w111_1, const float* __restrict__ b111_1,
    const float* __restrict__ w211_0, const float* __restrict__ b211_0,
    const float* __restrict__ w211_1, const float* __restrict__ b211_1) {
  __shared__ float sm[SMEM_FLOATS];
  __hip_bfloat16* hb = (__hip_bfloat16*)sm;

  const int bid = blockIdx.x;
  const int pl = bid >> 3;
  const int t = bid & 7;
  const int tR0 = (t >> 2) * 64;
  const int tC0 = (t & 3) * 32;
  const int ch = pl & (CC - 1);
  const float* xp = x + (size_t)pl * PLANE;
  float* Tp = T + (size_t)pl * TPSTR;
  const int tid = threadIdx.x;

  float* xbuf = sm + UNION_F;
  __hip_bfloat16* xsTh = hb + XSTH_H;
  const int base_r = tR0 - 11, base_c = tC0 - 12;

  // Border fixup geometry (pass-dependent row part handled below).
  int nbrJ = 0, brJ0 = 0;
  if (tC0 == 0) { nbrJ = 3; brJ0 = 0; }
  if (tC0 == 96) { nbrJ = 3; brJ0 = 10; }

  #pragma unroll
  for (int pass = 0; pass < 2; ++pass) {
    const int roff = pass * 42;
    const int rg_lo = pass * 14;
    // ---- phase A: load raw rows [roff, roff+44) of halo tile ----
    for (int i = tid; i < 44 * 14; i += 256) {
      int rr = i / 14;
      int jj = i - rr * 14;
      int gr = base_r + roff + rr;
      int gc = base_c + jj * 4;
      float4 v = make_float4(0.f, 0.f, 0.f, 0.f);
      if ((unsigned)gr < 128u && (unsigned)gc < 128u)
        v = *(const float4*)(xp + gr * WW + gc);
      *(float4*)(xbuf + rr * XRAW_STR + jj * 4) = v;
    }
    __syncthreads();
    // ---- phase A2 fast: all 182 items, unconditional interior math ----
    for (int i = tid; i < 14 * 13; i += 256) {
      int rg = rg_lo + (i % 14);
      int jj = i / 14;
      a2_item_fast(sm, xsTh, xbuf, rg, jj, roff);
    }
    __syncthreads();
    // ---- phase A2 fixup: compact border set, exact slow path ----
    int nbrR = 0, brR0 = 0;
    if (pass == 0 && tR0 == 0) { nbrR = 4; brR0 = 0; }
    if (pass == 1 && tR0 == 64) { nbrR = 4; brR0 = 10; }
    int nA = nbrR * 13;
    int nfix = nA + (14 - nbrR) * nbrJ;
    for (int i = tid; i < nfix; i += 256) {
      int rgl, jj;
      if (i < nA) {
        rgl = brR0 + i / 13;
        jj = i % 13;
      } else {
        int i2 = i - nA;
        jj = brJ0 + i2 % 3;
        int r = i2 / 3;
        rgl = (nbrR != 0 && brR0 == 0) ? (r + 4) : r;
      }
      a2_item_slow(sm, xsTh, xbuf, tR0, tC0, rg_lo + rgl, jj, roff);
    }
    __syncthreads();
  }

  float k7[7], k11[11], k21[21];
  #pragma unroll
  for (int i = 0; i < 7; ++i) k7[i] = w17_0[ch * 7 + i];
  #pragma unroll
  for (int i = 0; i < 11; ++i) k11[i] = w111_0[ch * 11 + i];
  #pragma unroll
  for (int i = 0; i < 21; ++i) k21[i] = w211_0[ch * 21 + i];
  float bb7 = 3.f * b17_0[ch];
  float bb11 = 3.f * b111_0[ch];
  float bb21 = 3.f * b211_0[ch];

  // ---- phase B: horizontal convs; [296 valid rows | 40 zero rows] split ----
  {
    const int rlo = (tR0 == 0) ? 10 : 0;   // valid rr range [rlo, rlo+73]
    const int ilo = (tR0 == 0) ? 0 : 74;   // invalid rr range [ilo, ilo+9]
    for (int it = tid; it < 336; it += 256) {
      if (it < 296) {
        int rr = rlo + it % 74;
        int cg = it / 74;
        float w[28];
        const float* xr = sm + rr * XS_STR + cg * 8;
        #pragma unroll
        for (int j = 0; j < 7; ++j) {
          float4 v = *(const float4*)(xr + 4 * j);
          w[4 * j] = v.x; w[4 * j + 1] = v.y;
          w[4 * j + 2] = v.z; w[4 * j + 3] = v.w;
        }
        bool v11r = (rr >= 5) && (rr <= 78);
        bool v7r = (rr >= 7) && (rr <= 76);
        #pragma unroll
        for (int j = 0; j < 8; ++j) {
          float a21 = bb21, a11 = bb11, a7 = bb7;
          #pragma unroll
          for (int d = 0; d < 21; ++d) a21 += k21[d] * w[j + d];
          #pragma unroll
          for (int d = 0; d < 11; ++d) a11 += k11[d] * w[j + 5 + d];
          #pragma unroll
          for (int d = 0; d < 7; ++d) a7 += k7[d] * w[j + 7 + d];
          int c = cg * 8 + j;
          hb[H21_H + c * 88 + rr] = __float2bfloat16(a21);
          if (v11r) hb[H11_H + c * 88 + rr - 5] = __float2bfloat16(a11);
          if (v7r) hb[H7_H + c * 88 + rr - 7] = __float2bfloat16(a7);
        }
      } else {
        int i2 = it - 296;
        int rr = ilo + i2 % 10;
        int cg = i2 / 10;
        bool v11r = (rr >= 5) && (rr <= 78);
        bool v7r = (rr >= 7) && (rr <= 76);
        __hip_bfloat16 z = __float2bfloat16(0.f);
        #pragma unroll
        for (int j = 0; j < 8; ++j) {
          int c = cg * 8 + j;
          hb[H21_H + c * 88 + rr] = z;
          if (v11r) hb[H11_H + c * 88 + rr - 5] = z;
          if (v7r) hb[H7_H + c * 88 + rr - 7] = z;
        }
      }
    }
  }

  float v7a[7], v11a[11], v21a[21], w5a[25];
  #pragma unroll
  for (int i = 0; i < 7; ++i) v7a[i] = w17_1[ch * 7 + i];
  #pragma unroll
  for (int i = 0; i < 11; ++i) v11a[i] = w111_1[ch * 11 + i];
  #pragma unroll
  for (int i = 0; i < 21; ++i) v21a[i] = w211_1[ch * 21 + i];
  #pragma unroll
  for (int i = 0; i < 25; ++i) w5a[i] = w55[ch * 25 + i];
  float bsum = 3.f * (b55[ch] + b17_1[ch] + b111_1[ch] + b211_1[ch]);

  __syncthreads();

  // ---- phase C: vertical convs + 5x5; 8 rows/thread along a column ----
  {
    int c = tid & 31;
    int r0 = (tid >> 5) * 8;
    float acc[8];
    #pragma unroll
    for (int j = 0; j < 8; ++j) acc[j] = bsum;

    float A[28];
    {  // h21: indices r0..r0+27 (28 halves)
      const unsigned* p = (const unsigned*)&hb[H21_H + c * 88 + r0];
      uint4 q0 = *(const uint4*)p;
      uint4 q1 = *(const uint4*)(p + 4);
      uint4 q2 = *(const uint4*)(p + 8);
      uint2 q3 = *(const uint2*)(p + 12);
      A[0]=lo16(q0.x);A[1]=hi16(q0.x);A[2]=lo16(q0.y);A[3]=hi16(q0.y);
      A[4]=lo16(q0.z);A[5]=hi16(q0.z);A[6]=lo16(q0.w);A[7]=hi16(q0.w);
      A[8]=lo16(q1.x);A[9]=hi16(q1.x);A[10]=lo16(q1.y);A[11]=hi16(q1.y);
      A[12]=lo16(q1.z);A[13]=hi16(q1.z);A[14]=lo16(q1.w);A[15]=hi16(q1.w);
      A[16]=lo16(q2.x);A[17]=hi16(q2.x);A[18]=lo16(q2.y);A[19]=hi16(q2.y);
      A[20]=lo16(q2.z);A[21]=hi16(q2.z);A[22]=lo16(q2.w);A[23]=hi16(q2.w);
      A[24]=lo16(q3.x);A[25]=hi16(q3.x);A[26]=lo16(q3.y);A[27]=hi16(q3.y);
      #pragma unroll
      for (int d = 0; d < 21; ++d)
        #pragma unroll
        for (int j = 0; j < 8; ++j) acc[j] += v21a[d] * A[d + j];
    }
    {  // h11: indices r0..r0+17 (18 halves, read 20)
      const unsigned* p = (const unsigned*)&hb[H11_H + c * 88 + r0];
      uint4 q0 = *(const uint4*)p;
      uint4 q1 = *(const uint4*)(p + 4);
      uint2 q2 = *(const uint2*)(p + 8);
      A[0]=lo16(q0.x);A[1]=hi16(q0.x);A[2]=lo16(q0.y);A[3]=hi16(q0.y);
      A[4]=lo16(q0.z);A[5]=hi16(q0.z);A[6]=lo16(q0.w);A[7]=hi16(q0.w);
      A[8]=lo16(q1.x);A[9]=hi16(q1.x);A[10]=lo16(q1.y);A[11]=hi16(q1.y);
      A[12]=lo16(q1.z);A[13]=hi16(q1.z);A[14]=lo16(q1.w);A[15]=hi16(q1.w);
      A[16]=lo16(q2.x);A[17]=hi16(q2.x);
      #pragma unroll
      for (int d = 0; d < 11; ++d)
        #pragma unroll
        for (int j = 0; j < 8; ++j) acc[j] += v11a[d] * A[d + j];
    }
    {  // h7: indices r0..r0+13 (14 halves, read 16)
      const unsigned* p = (const unsigned*)&hb[H7_H + c * 88 + r0];
      uint4 q0 = *(const uint4*)p;
      uint4 q1 = *(const uint4*)(p + 4);
      A[0]=lo16(q0.x);A[1]=hi16(q0.x);A[2]=lo16(q0.y);A[3]=hi16(q0.y);
      A[4]=lo16(q0.z);A[5]=hi16(q0.z);A[6]=lo16(q0.w);A[7]=hi16(q0.w);
      A[8]=lo16(q1.x);A[9]=hi16(q1.x);A[10]=lo16(q1.y);A[11]=hi16(q1.y);
      A[12]=lo16(q1.z);A[13]=hi16(q1.z);
      #pragma unroll
      for (int d = 0; d < 7; ++d)
        #pragma unroll
        for (int j = 0; j < 8; ++j) acc[j] += v7a[d] * A[d + j];
    }
    {  // 5x5 from bf16 transposed U: cols c..c+4, rows r0..r0+11
      #pragma unroll
      for (int dc = 0; dc < 5; ++dc) {
        const unsigned* p = (const unsigned*)&hb[XSTH_H + (c + dc) * 72 + r0];
        uint4 q0 = *(const uint4*)p;
        uint2 q1 = *(const uint2*)(p + 4);
        float X[12];
        X[0]=lo16(q0.x);X[1]=hi16(q0.x);X[2]=lo16(q0.y);X[3]=hi16(q0.y);
        X[4]=lo16(q0.z);X[5]=hi16(q0.z);X[6]=lo16(q0.w);X[7]=hi16(q0.w);
        X[8]=lo16(q1.x);X[9]=hi16(q1.x);X[10]=lo16(q1.y);X[11]=hi16(q1.y);
        #pragma unroll
        for (int dr = 0; dr < 5; ++dr)
          #pragma unroll
          for (int j = 0; j < 8; ++j) acc[j] += w5a[dr * 5 + dc] * X[j + dr];
      }
    }
    #pragma unroll
    for (int j = 0; j < 8; ++j)
      Tp[(size_t)(tR0 + r0 + j) * WW + tC0 + c] = acc[j];
  }
}

// ---------------------------------------------------------------------------
// k_mix: out = (W11 . T + 3*b11) * x.  v5: 256 px x 64 co per block, thread =
// 4 px x 16 co.  v1's proven barrier-free direct-global structure (float4 T
// loads, 2-slot register ring), with T redundancy cut 8x->4x by the bigger
// px block, and cog == wave index so all W LDS reads are wave-uniform
// broadcasts (free).  k-order (ci ascending) identical to all prior versions.
// ---------------------------------------------------------------------------
__global__ __launch_bounds__(256, 4) void k_mix(const float* __restrict__ T,
                                                const float* __restrict__ x,
                                                const float* __restrict__ w11,
                                                const float* __restrict__ b11,
                                                float* __restrict__ out) {
  __shared__ float Wt[64 * 68];              // [ci][co], stride 68

  int bid = blockIdx.x;
  int b = bid >> 6;
  int px0 = (bid & 63) * 256;
  int tid = threadIdx.x;

  for (int i = tid; i < 4096; i += 256) {
    int co = i >> 6, ci = i & 63;
    Wt[ci * 68 + co] = w11[i];
  }

  int pxg = tid & 63;                        // 64 groups x 4 px = 256 px
  int cog = tid >> 6;                        // wave index = co group (16 co)
  const float* Tb = T + (size_t)b * 64 * TPSTR + px0 + pxg * 4;
  const float* wp = Wt + cog * 16;

  float4 tb0[4], tb1[4];
  #pragma unroll
  for (int kk = 0; kk < 4; ++kk)
    tb0[kk] = *(const float4*)(Tb + (size_t)kk * TPSTR);

  __syncthreads();

  float acc[16][4];
  #pragma unroll
  for (int a = 0; a < 16; ++a)
    #pragma unroll
    for (int p = 0; p < 4; ++p) acc[a][p] = 0.f;

  #pragma unroll
  for (int kc = 0; kc < 16; ++kc) {
    float4* cur = (kc & 1) ? tb1 : tb0;      // static after full unroll
    float4* nxt = (kc & 1) ? tb0 : tb1;
    if (kc < 15) {
      #pragma unroll
      for (int kk = 0; kk < 4; ++kk)
        nxt[kk] = *(const float4*)(Tb + (size_t)(kc * 4 + 4 + kk) * TPSTR);
    }
    #pragma unroll
    for (int kk = 0; kk < 4; ++kk) {
      int k = kc * 4 + kk;
      const float* wr = wp + k * 68;         // wave-uniform -> LDS broadcast
      float4 tv = cur[kk];
      float tvv[4] = {tv.x, tv.y, tv.z, tv.w};
      #pragma unroll
      for (int g = 0; g < 4; ++g) {
        float4 qg = *(const float4*)(wr + g * 4);
        float wf4[4] = {qg.x, qg.y, qg.z, qg.w};
        #pragma unroll
        for (int a = 0; a < 4; ++a)
          #pragma unroll
          for (int p = 0; p < 4; ++p)
            acc[g * 4 + a][p] += wf4[a] * tvv[p];
      }
    }
  }

  const float* xb = x + (size_t)b * (CC * PLANE) + px0 + pxg * 4;
  float* ob = out + (size_t)b * (CC * PLANE) + px0 + pxg * 4;
  #pragma unroll
  for (int a = 0; a < 16; ++a) {
    int co = cog * 16 + a;
    float bb = 3.f * b11[co];
    float4 xv = *(const float4*)(xb + (size_t)co * PLANE);
    float4 o;
    o.x = (acc[a][0] + bb) * xv.x;
    o.y = (acc[a][1] + bb) * xv.y;
    o.z = (acc[a][2] + bb) * xv.z;
    o.w = (acc[a][3] + bb) * xv.w;
    *(float4*)(ob + (size_t)co * PLANE) = o;
  }
}

extern "C" void kernel_launch(void* const* d_in, const int* in_sizes, int n_in,
                              void* d_out, int out_size, void* d_ws,
                              size_t ws_size, hipStream_t stream) {
  const float* x = (const float*)d_in[0];
  const float* w55 = (const float*)d_in[1];
  const float* b55 = (const float*)d_in[2];
  const float* w17_0 = (const float*)d_in[3];
  const float* b17_0 = (const float*)d_in[4];
  const float* w17_1 = (const float*)d_in[5];
  const float* b17_1 = (const float*)d_in[6];
  const float* w111_0 = (const float*)d_in[7];
  const float* b111_0 = (const float*)d_in[8];
  const float* w111_1 = (const float*)d_in[9];
  const float* b111_1 = (const float*)d_in[10];
  const float* w211_0 = (const float*)d_in[11];
  const float* b211_0 = (const float*)d_in[12];
  const float* w211_1 = (const float*)d_in[13];
  const float* b211_1 = (const float*)d_in[14];
  const float* w11 = (const float*)d_in[15];
  const float* b11 = (const float*)d_in[16];
  float* outp = (float*)d_out;

  float* T = (float*)d_ws;                 // [16*64][TPSTR]

  k_dwsum<<<BB * CC * 8, 256, 0, stream>>>(
      x, T, w55, b55, w17_0, b17_0, w17_1, b17_1, w111_0, b111_0, w111_1,
      b111_1, w211_0, b211_0, w211_1, b211_1);
  k_mix<<<BB * 64, 256, 0, stream>>>(T, x, w11, b11, outp);
}

// Round 5
// 292.721 us; speedup vs baseline: 2.4510x; 2.4510x over previous
//
#include <hip/hip_runtime.h>
#include <hip/hip_bf16.h>
#include <cstdint>

#define HH 128
#define WW 128
#define CC 64
#define BB 16
#define PLANE (HH*WW)
#define TPSTR 16512   // T plane stride: 16384 + 128 floats (512 B pad) breaks
                      // the 64-KB power-of-2 channel/set aliasing in k_mix.

// k_dwsum LDS layout (two-pass xbuf -> 39552 B -> 4 blocks/CU).
//   xs   [84][52] f32  U row-major, rows -10..73, cols -10..41
//   xsTh [36][72] bf16 U col-major, cols -2..33, rows -2..65
//   h7T  [32][88] bf16 rows -3..66 (70 used)
//   union { xbuf [44][60] f32 (phase A, two passes: raw rows 0..43 / 42..85)
//         | h11T [32][88] bf16 ; h21T [32][88] bf16 }
#define XS_STR    52
#define XRAW_STR  60
#define XSTH_H    8736    // half-index of xsTh   (= 4368 floats * 2)
#define H7_H      11328   // half-index of h7T    (= 5664 floats * 2)
#define UNION_F   7072    // float-index of xbuf
#define H11_H     14144   // half-index of h11T   (inside union)
#define H21_H     16960   // half-index of h21T   (inside union)
#define SMEM_FLOATS 9888  // 39552 B -> 4 blocks/CU

__device__ __forceinline__ float lo16(unsigned int u) {
  return __uint_as_float(u << 16);
}
__device__ __forceinline__ float hi16(unsigned int u) {
  return __uint_as_float(u & 0xffff0000u);
}

__device__ __forceinline__ void a2_store(float* sm, __hip_bfloat16* xsTh,
                                         int rr, int jj, const float uq[4]) {
  *(float4*)(sm + rr * XS_STR + jj * 4) =
      make_float4(uq[0], uq[1], uq[2], uq[3]);
  int rt = rr - 8;                       // xsTh row (tile row -2..65)
  if ((unsigned)rt < 68u) {
    #pragma unroll
    for (int q = 0; q < 4; ++q) {
      int ct = jj * 4 + q - 8;           // xsTh col (tile col -2..33)
      if ((unsigned)ct < 36u)
        xsTh[ct * 72 + rt] = __float2bfloat16(uq[q]);
    }
  }
}

// Fast path: no border masking (valid only for interior items; border items
// get overwritten by the fixup pass). Factored column sums/maxes.
__device__ __forceinline__ void a2_item_fast(float* sm, __hip_bfloat16* xsTh,
                                             const float* xbuf, int rg,
                                             int jj, int roff) {
  int rr0 = rg * 3;
  const float* rp = xbuf + (rr0 - roff) * XRAW_STR + jj * 4;
  float w[5][8];
  #pragma unroll
  for (int k = 0; k < 5; ++k) {
    float4 a = *(const float4*)(rp + k * XRAW_STR);
    float4 b = *(const float4*)(rp + k * XRAW_STR + 4);
    w[k][0] = a.x; w[k][1] = a.y; w[k][2] = a.z; w[k][3] = a.w;
    w[k][4] = b.x; w[k][5] = b.y; w[k][6] = b.z; w[k][7] = b.w;
  }
  float cs[3][7], cm[3][7];
  #pragma unroll
  for (int p = 1; p <= 6; ++p) {
    float a0 = w[0][p], a1 = w[1][p], a2 = w[2][p], a3 = w[3][p],
          a4 = w[4][p];
    float s12 = a1 + a2;
    cs[0][p] = a0 + s12;
    cs[1][p] = s12 + a3;
    float s34 = a3 + a4;
    cs[2][p] = a2 + s34;
    float m12 = fmaxf(a1, a2);
    cm[0][p] = fmaxf(a0, m12);
    cm[1][p] = fmaxf(m12, a3);
    float m34 = fmaxf(a3, a4);
    cm[2][p] = fmaxf(a2, m34);
  }
  #pragma unroll
  for (int k = 0; k < 3; ++k) {
    float t23 = cs[k][2] + cs[k][3];
    float t45 = cs[k][4] + cs[k][5];
    float n23 = fmaxf(cm[k][2], cm[k][3]);
    float n45 = fmaxf(cm[k][4], cm[k][5]);
    float uq[4];
    uq[0] = w[k + 1][2] + (cs[k][1] + t23) * (1.f / 9.f) +
            fmaxf(cm[k][1], n23);
    uq[1] = w[k + 1][3] + (t23 + cs[k][4]) * (1.f / 9.f) +
            fmaxf(n23, cm[k][4]);
    uq[2] = w[k + 1][4] + (cs[k][3] + t45) * (1.f / 9.f) +
            fmaxf(cm[k][3], n45);
    uq[3] = w[k + 1][5] + (t45 + cs[k][6]) * (1.f / 9.f) +
            fmaxf(n45, cm[k][6]);
    a2_store(sm, xsTh, rr0 + k, jj, uq);
  }
}

// Slow path: verbatim original masked math (exact at borders).
__device__ __forceinline__ void a2_item_slow(float* sm, __hip_bfloat16* xsTh,
                                             const float* xbuf, int tR0,
                                             int tC0, int rg, int jj,
                                             int roff) {
  int rr0 = rg * 3;
  const float* rp = xbuf + (rr0 - roff) * XRAW_STR + jj * 4;
  float w[5][8];
  #pragma unroll
  for (int k = 0; k < 5; ++k) {
    float4 a = *(const float4*)(rp + k * XRAW_STR);
    float4 b = *(const float4*)(rp + k * XRAW_STR + 4);
    w[k][0] = a.x; w[k][1] = a.y; w[k][2] = a.z; w[k][3] = a.w;
    w[k][4] = b.x; w[k][5] = b.y; w[k][6] = b.z; w[k][7] = b.w;
  }
  int gc0 = tC0 + jj * 4 - 12;
  bool cv[7];
  #pragma unroll
  for (int p = 1; p <= 6; ++p) cv[p] = (unsigned)(gc0 + p) < 128u;

  #pragma unroll
  for (int k = 0; k < 3; ++k) {
    int rr = rr0 + k;
    int gr = tR0 + rr - 10;
    bool rv0 = (unsigned)(gr - 1) < 128u;
    bool rv1 = (unsigned)(gr) < 128u;
    bool rv2 = (unsigned)(gr + 1) < 128u;
    float M0[7], M1[7], M2[7];
    #pragma unroll
    for (int p = 1; p <= 6; ++p) {
      M0[p] = (rv0 && cv[p]) ? w[k][p] : -3.402823466e38f;
      M1[p] = (rv1 && cv[p]) ? w[k + 1][p] : -3.402823466e38f;
      M2[p] = (rv2 && cv[p]) ? w[k + 2][p] : -3.402823466e38f;
    }
    float uq[4];
    #pragma unroll
    for (int q = 0; q < 4; ++q) {
      float s = w[k][q + 1] + w[k][q + 2] + w[k][q + 3] + w[k + 1][q + 1] +
                w[k + 1][q + 2] + w[k + 1][q + 3] + w[k + 2][q + 1] +
                w[k + 2][q + 2] + w[k + 2][q + 3];
      float m = fmaxf(
          fmaxf(fmaxf(M0[q + 1], M0[q + 2]), fmaxf(M0[q + 3], M1[q + 1])),
          fmaxf(fmaxf(M1[q + 2], M1[q + 3]),
                fmaxf(fmaxf(M2[q + 1], M2[q + 2]), M2[q + 3])));
      float val = w[k + 1][q + 2] + s * (1.f / 9.f) + m;
      bool vo = rv1 && ((unsigned)(gc0 + q + 2) < 128u);
      uq[q] = vo ? val : 0.f;
    }
    a2_store(sm, xsTh, rr, jj, uq);
  }
}

__global__ __launch_bounds__(256, 4) void k_dwsum(
    const float* __restrict__ x, float* __restrict__ T,
    const float* __restrict__ w55, const float* __restrict__ b55,
    const float* __restrict__ w17_0, const float* __restrict__ b17_0,
    const float* __restrict__ w17_1, const float* __restrict__ b17_1,
    const float* __restrict__ w111_0, const float* __restrict__ b111_0,
    const float* __restrict__ w111_1, const float* __restrict__ b111_1,
    const float* __restrict__ w211_0, const float* __restrict__ b211_0,
    const float* __restrict__ w211_1, const float* __restrict__ b211_1) {
  __shared__ float sm[SMEM_FLOATS];
  __hip_bfloat16* hb = (__hip_bfloat16*)sm;

  const int bid = blockIdx.x;
  const int pl = bid >> 3;
  const int t = bid & 7;
  const int tR0 = (t >> 2) * 64;
  const int tC0 = (t & 3) * 32;
  const int ch = pl & (CC - 1);
  const float* xp = x + (size_t)pl * PLANE;
  float* Tp = T + (size_t)pl * TPSTR;
  const int tid = threadIdx.x;

  float* xbuf = sm + UNION_F;
  __hip_bfloat16* xsTh = hb + XSTH_H;
  const int base_r = tR0 - 11, base_c = tC0 - 12;

  // Border fixup geometry (col part; row part is pass-dependent).
  int nbrJ = 0, brJ0 = 0;
  if (tC0 == 0) { nbrJ = 3; brJ0 = 0; }
  if (tC0 == 96) { nbrJ = 3; brJ0 = 10; }

  // ROLLED pass loop (v4's unrolled version doubled the inlined A2 bodies and
  // spilled under the 128-VGPR cap of __launch_bounds__(256,4)).
  for (int pass = 0; pass < 2; ++pass) {
    const int roff = pass * 42;
    const int rg_lo = pass * 14;
    // ---- phase A: load raw rows [roff, roff+44) of halo tile ----
    for (int i = tid; i < 44 * 14; i += 256) {
      int rr = i / 14;
      int jj = i - rr * 14;
      int gr = base_r + roff + rr;
      int gc = base_c + jj * 4;
      float4 v = make_float4(0.f, 0.f, 0.f, 0.f);
      if ((unsigned)gr < 128u && (unsigned)gc < 128u)
        v = *(const float4*)(xp + gr * WW + gc);
      *(float4*)(xbuf + rr * XRAW_STR + jj * 4) = v;
    }
    __syncthreads();
    // ---- phase A2 fast: all 182 items, unconditional interior math ----
    for (int i = tid; i < 14 * 13; i += 256) {
      int rg = rg_lo + (i % 14);
      int jj = i / 14;
      a2_item_fast(sm, xsTh, xbuf, rg, jj, roff);
    }
    __syncthreads();
    // ---- phase A2 fixup: compact border set, exact slow path ----
    int nbrR = 0, brR0 = 0;
    if (pass == 0 && tR0 == 0) { nbrR = 4; brR0 = 0; }
    if (pass == 1 && tR0 == 64) { nbrR = 4; brR0 = 10; }
    int nA = nbrR * 13;
    int nfix = nA + (14 - nbrR) * nbrJ;
    for (int i = tid; i < nfix; i += 256) {
      int rgl, jj;
      if (i < nA) {
        rgl = brR0 + i / 13;
        jj = i % 13;
      } else {
        int i2 = i - nA;
        jj = brJ0 + i2 % 3;
        int r = i2 / 3;
        rgl = (nbrR != 0 && brR0 == 0) ? (r + 4) : r;
      }
      a2_item_slow(sm, xsTh, xbuf, tR0, tC0, rg_lo + rgl, jj, roff);
    }
    __syncthreads();
  }

  float k7[7], k11[11], k21[21];
  #pragma unroll
  for (int i = 0; i < 7; ++i) k7[i] = w17_0[ch * 7 + i];
  #pragma unroll
  for (int i = 0; i < 11; ++i) k11[i] = w111_0[ch * 11 + i];
  #pragma unroll
  for (int i = 0; i < 21; ++i) k21[i] = w211_0[ch * 21 + i];
  float bb7 = 3.f * b17_0[ch];
  float bb11 = 3.f * b111_0[ch];
  float bb21 = 3.f * b211_0[ch];

  // ---- phase B: horizontal convs; [296 valid rows | 40 zero rows] split ----
  {
    const int rlo = (tR0 == 0) ? 10 : 0;   // valid rr range [rlo, rlo+73]
    const int ilo = (tR0 == 0) ? 0 : 74;   // invalid rr range [ilo, ilo+9]
    for (int it = tid; it < 336; it += 256) {
      if (it < 296) {
        int rr = rlo + it % 74;
        int cg = it / 74;
        float w[28];
        const float* xr = sm + rr * XS_STR + cg * 8;
        #pragma unroll
        for (int j = 0; j < 7; ++j) {
          float4 v = *(const float4*)(xr + 4 * j);
          w[4 * j] = v.x; w[4 * j + 1] = v.y;
          w[4 * j + 2] = v.z; w[4 * j + 3] = v.w;
        }
        bool v11r = (rr >= 5) && (rr <= 78);
        bool v7r = (rr >= 7) && (rr <= 76);
        #pragma unroll
        for (int j = 0; j < 8; ++j) {
          float a21 = bb21, a11 = bb11, a7 = bb7;
          #pragma unroll
          for (int d = 0; d < 21; ++d) a21 += k21[d] * w[j + d];
          #pragma unroll
          for (int d = 0; d < 11; ++d) a11 += k11[d] * w[j + 5 + d];
          #pragma unroll
          for (int d = 0; d < 7; ++d) a7 += k7[d] * w[j + 7 + d];
          int c = cg * 8 + j;
          hb[H21_H + c * 88 + rr] = __float2bfloat16(a21);
          if (v11r) hb[H11_H + c * 88 + rr - 5] = __float2bfloat16(a11);
          if (v7r) hb[H7_H + c * 88 + rr - 7] = __float2bfloat16(a7);
        }
      } else {
        int i2 = it - 296;
        int rr = ilo + i2 % 10;
        int cg = i2 / 10;
        bool v11r = (rr >= 5) && (rr <= 78);
        bool v7r = (rr >= 7) && (rr <= 76);
        __hip_bfloat16 z = __float2bfloat16(0.f);
        #pragma unroll
        for (int j = 0; j < 8; ++j) {
          int c = cg * 8 + j;
          hb[H21_H + c * 88 + rr] = z;
          if (v11r) hb[H11_H + c * 88 + rr - 5] = z;
          if (v7r) hb[H7_H + c * 88 + rr - 7] = z;
        }
      }
    }
  }

  float v7a[7], v11a[11], v21a[21], w5a[25];
  #pragma unroll
  for (int i = 0; i < 7; ++i) v7a[i] = w17_1[ch * 7 + i];
  #pragma unroll
  for (int i = 0; i < 11; ++i) v11a[i] = w111_1[ch * 11 + i];
  #pragma unroll
  for (int i = 0; i < 21; ++i) v21a[i] = w211_1[ch * 21 + i];
  #pragma unroll
  for (int i = 0; i < 25; ++i) w5a[i] = w55[ch * 25 + i];
  float bsum = 3.f * (b55[ch] + b17_1[ch] + b111_1[ch] + b211_1[ch]);

  __syncthreads();

  // ---- phase C: vertical convs + 5x5; 8 rows/thread along a column ----
  {
    int c = tid & 31;
    int r0 = (tid >> 5) * 8;
    float acc[8];
    #pragma unroll
    for (int j = 0; j < 8; ++j) acc[j] = bsum;

    float A[28];
    {  // h21: indices r0..r0+27 (28 halves)
      const unsigned* p = (const unsigned*)&hb[H21_H + c * 88 + r0];
      uint4 q0 = *(const uint4*)p;
      uint4 q1 = *(const uint4*)(p + 4);
      uint4 q2 = *(const uint4*)(p + 8);
      uint2 q3 = *(const uint2*)(p + 12);
      A[0]=lo16(q0.x);A[1]=hi16(q0.x);A[2]=lo16(q0.y);A[3]=hi16(q0.y);
      A[4]=lo16(q0.z);A[5]=hi16(q0.z);A[6]=lo16(q0.w);A[7]=hi16(q0.w);
      A[8]=lo16(q1.x);A[9]=hi16(q1.x);A[10]=lo16(q1.y);A[11]=hi16(q1.y);
      A[12]=lo16(q1.z);A[13]=hi16(q1.z);A[14]=lo16(q1.w);A[15]=hi16(q1.w);
      A[16]=lo16(q2.x);A[17]=hi16(q2.x);A[18]=lo16(q2.y);A[19]=hi16(q2.y);
      A[20]=lo16(q2.z);A[21]=hi16(q2.z);A[22]=lo16(q2.w);A[23]=hi16(q2.w);
      A[24]=lo16(q3.x);A[25]=hi16(q3.x);A[26]=lo16(q3.y);A[27]=hi16(q3.y);
      #pragma unroll
      for (int d = 0; d < 21; ++d)
        #pragma unroll
        for (int j = 0; j < 8; ++j) acc[j] += v21a[d] * A[d + j];
    }
    {  // h11: indices r0..r0+17 (18 halves, read 20)
      const unsigned* p = (const unsigned*)&hb[H11_H + c * 88 + r0];
      uint4 q0 = *(const uint4*)p;
      uint4 q1 = *(const uint4*)(p + 4);
      uint2 q2 = *(const uint2*)(p + 8);
      A[0]=lo16(q0.x);A[1]=hi16(q0.x);A[2]=lo16(q0.y);A[3]=hi16(q0.y);
      A[4]=lo16(q0.z);A[5]=hi16(q0.z);A[6]=lo16(q0.w);A[7]=hi16(q0.w);
      A[8]=lo16(q1.x);A[9]=hi16(q1.x);A[10]=lo16(q1.y);A[11]=hi16(q1.y);
      A[12]=lo16(q1.z);A[13]=hi16(q1.z);A[14]=lo16(q1.w);A[15]=hi16(q1.w);
      A[16]=lo16(q2.x);A[17]=hi16(q2.x);
      #pragma unroll
      for (int d = 0; d < 11; ++d)
        #pragma unroll
        for (int j = 0; j < 8; ++j) acc[j] += v11a[d] * A[d + j];
    }
    {  // h7: indices r0..r0+13 (14 halves, read 16)
      const unsigned* p = (const unsigned*)&hb[H7_H + c * 88 + r0];
      uint4 q0 = *(const uint4*)p;
      uint4 q1 = *(const uint4*)(p + 4);
      A[0]=lo16(q0.x);A[1]=hi16(q0.x);A[2]=lo16(q0.y);A[3]=hi16(q0.y);
      A[4]=lo16(q0.z);A[5]=hi16(q0.z);A[6]=lo16(q0.w);A[7]=hi16(q0.w);
      A[8]=lo16(q1.x);A[9]=hi16(q1.x);A[10]=lo16(q1.y);A[11]=hi16(q1.y);
      A[12]=lo16(q1.z);A[13]=hi16(q1.z);
      #pragma unroll
      for (int d = 0; d < 7; ++d)
        #pragma unroll
        for (int j = 0; j < 8; ++j) acc[j] += v7a[d] * A[d + j];
    }
    {  // 5x5 from bf16 transposed U: cols c..c+4, rows r0..r0+11
      #pragma unroll
      for (int dc = 0; dc < 5; ++dc) {
        const unsigned* p = (const unsigned*)&hb[XSTH_H + (c + dc) * 72 + r0];
        uint4 q0 = *(const uint4*)p;
        uint2 q1 = *(const uint2*)(p + 4);
        float X[12];
        X[0]=lo16(q0.x);X[1]=hi16(q0.x);X[2]=lo16(q0.y);X[3]=hi16(q0.y);
        X[4]=lo16(q0.z);X[5]=hi16(q0.z);X[6]=lo16(q0.w);X[7]=hi16(q0.w);
        X[8]=lo16(q1.x);X[9]=hi16(q1.x);X[10]=lo16(q1.y);X[11]=hi16(q1.y);
        #pragma unroll
        for (int dr = 0; dr < 5; ++dr)
          #pragma unroll
          for (int j = 0; j < 8; ++j) acc[j] += w5a[dr * 5 + dc] * X[j + dr];
      }
    }
    #pragma unroll
    for (int j = 0; j < 8; ++j)
      Tp[(size_t)(tR0 + r0 + j) * WW + tC0 + c] = acc[j];
  }
}

// ---------------------------------------------------------------------------
// k_mix: out = (W11 . T + 3*b11) * x.  T has padded plane stride TPSTR.
// EXACT v1 (best measured ~127 us): 128 px x 64 co per block, 4 px x 8 co per
// thread, 3-slot (2-chunk-deep) register prefetch ring for T, plain
// __launch_bounds__(256) -- NO min-waves bound (v5's (256,4) capped VGPR at
// 128 and spilled the accumulator to scratch: 666 MB writes, 3.6x slower).
// ---------------------------------------------------------------------------
__global__ __launch_bounds__(256) void k_mix(const float* __restrict__ T,
                                             const float* __restrict__ x,
                                             const float* __restrict__ w11,
                                             const float* __restrict__ b11,
                                             float* __restrict__ out) {
  __shared__ float Wt[64 * 68];            // [ci][co], stride 68
  int bid = blockIdx.x;
  int b = bid >> 7;
  int px0 = (bid & 127) * 128;
  int tid = threadIdx.x;

  for (int i = tid; i < 4096; i += 256) {
    int co = i >> 6, ci = i & 63;
    Wt[ci * 68 + co] = w11[i];
  }
  __syncthreads();

  int pxg = tid & 31;                      // 32 groups x 4 px
  int cog = tid >> 5;                      // 8 groups x 8 co
  const float* Tb = T + (size_t)b * 64 * TPSTR + px0 + pxg * 4;
  const float* wp = Wt + cog * 8;

  float acc[8][4];
  #pragma unroll
  for (int a = 0; a < 8; ++a)
    #pragma unroll
    for (int p = 0; p < 4; ++p) acc[a][p] = 0.f;

  float4 tb[3][4];
  #pragma unroll
  for (int kk = 0; kk < 4; ++kk)
    tb[0][kk] = *(const float4*)(Tb + (size_t)kk * TPSTR);
  #pragma unroll
  for (int kk = 0; kk < 4; ++kk)
    tb[1][kk] = *(const float4*)(Tb + (size_t)(4 + kk) * TPSTR);

  #pragma unroll
  for (int kc = 0; kc < 16; ++kc) {
    const int cur = kc % 3;
    if (kc < 14) {
      const int nxt = (kc + 2) % 3;
      #pragma unroll
      for (int kk = 0; kk < 4; ++kk)
        tb[nxt][kk] =
            *(const float4*)(Tb + (size_t)((kc + 2) * 4 + kk) * TPSTR);
    }
    #pragma unroll
    for (int kk = 0; kk < 4; ++kk) {
      int k = kc * 4 + kk;
      float4 q0 = *(const float4*)(wp + k * 68);
      float4 q1 = *(const float4*)(wp + k * 68 + 4);
      float wf[8] = {q0.x, q0.y, q0.z, q0.w, q1.x, q1.y, q1.z, q1.w};
      float4 tv = tb[cur][kk];
      float tvv[4] = {tv.x, tv.y, tv.z, tv.w};
      #pragma unroll
      for (int a = 0; a < 8; ++a)
        #pragma unroll
        for (int p = 0; p < 4; ++p) acc[a][p] += wf[a] * tvv[p];
    }
  }

  const float* xb = x + (size_t)b * (CC * PLANE) + px0 + pxg * 4;
  float* ob = out + (size_t)b * (CC * PLANE) + px0 + pxg * 4;
  #pragma unroll
  for (int a = 0; a < 8; ++a) {
    int co = cog * 8 + a;
    float bb = 3.f * b11[co];
    float4 xv = *(const float4*)(xb + (size_t)co * PLANE);
    float4 o;
    o.x = (acc[a][0] + bb) * xv.x;
    o.y = (acc[a][1] + bb) * xv.y;
    o.z = (acc[a][2] + bb) * xv.z;
    o.w = (acc[a][3] + bb) * xv.w;
    *(float4*)(ob + (size_t)co * PLANE) = o;
  }
}

extern "C" void kernel_launch(void* const* d_in, const int* in_sizes, int n_in,
                              void* d_out, int out_size, void* d_ws,
                              size_t ws_size, hipStream_t stream) {
  const float* x = (const float*)d_in[0];
  const float* w55 = (const float*)d_in[1];
  const float* b55 = (const float*)d_in[2];
  const float* w17_0 = (const float*)d_in[3];
  const float* b17_0 = (const float*)d_in[4];
  const float* w17_1 = (const float*)d_in[5];
  const float* b17_1 = (const float*)d_in[6];
  const float* w111_0 = (const float*)d_in[7];
  const float* b111_0 = (const float*)d_in[8];
  const float* w111_1 = (const float*)d_in[9];
  const float* b111_1 = (const float*)d_in[10];
  const float* w211_0 = (const float*)d_in[11];
  const float* b211_0 = (const float*)d_in[12];
  const float* w211_1 = (const float*)d_in[13];
  const float* b211_1 = (const float*)d_in[14];
  const float* w11 = (const float*)d_in[15];
  const float* b11 = (const float*)d_in[16];
  float* outp = (float*)d_out;

  float* T = (float*)d_ws;                 // [16*64][TPSTR]

  k_dwsum<<<BB * CC * 8, 256, 0, stream>>>(
      x, T, w55, b55, w17_0, b17_0, w17_1, b17_1, w111_0, b111_0, w111_1,
      b111_1, w211_0, b211_0, w211_1, b211_1);
  k_mix<<<BB * 128, 256, 0, stream>>>(T, x, w11, b11, outp);
}

// Round 6
// 284.790 us; speedup vs baseline: 2.5193x; 1.0278x over previous
//
#include <hip/hip_runtime.h>
#include <hip/hip_bf16.h>
#include <cstdint>

#define HH 128
#define WW 128
#define CC 64
#define BB 16
#define PLANE (HH*WW)
#define TPSTR 16512   // T plane stride: 16384 + 128 floats (512 B pad) breaks
                      // the 64-KB power-of-2 channel/set aliasing in k_mix.

// k_dwsum LDS layout (two-pass xbuf -> 39552 B -> 4 blocks/CU).
//   xs   [84][52] f32  U row-major, rows -10..73, cols -10..41
//   xsTh [36][72] bf16 U col-major, cols -2..33, rows -2..65
//   h7T  [32][88] bf16 rows -3..66 (70 used)
//   union { xbuf [44][60] f32 (phase A, two passes: raw rows 0..43 / 42..85)
//         | h11T [32][88] bf16 ; h21T [32][88] bf16 }
#define XS_STR    52
#define XRAW_STR  60
#define XSTH_H    8736    // half-index of xsTh   (= 4368 floats * 2)
#define H7_H      11328   // half-index of h7T    (= 5664 floats * 2)
#define UNION_F   7072    // float-index of xbuf
#define H11_H     14144   // half-index of h11T   (inside union)
#define H21_H     16960   // half-index of h21T   (inside union)
#define SMEM_FLOATS 9888  // 39552 B -> 4 blocks/CU

__device__ __forceinline__ float lo16(unsigned int u) {
  return __uint_as_float(u << 16);
}
__device__ __forceinline__ float hi16(unsigned int u) {
  return __uint_as_float(u & 0xffff0000u);
}

// A2 half-pass: U = x + avg3 + max3 for rg in [rg_lo, rg_lo+14).
// xbuf holds raw rows [roff, roff+44) of the halo tile.
// (round-2 version: single masked path; measured 145 us / VALUBusy 80%.
//  The round-3 fast+fixup split measured 156 us: extra barriers + divergent
//  fixup cost more than the saved VALU ops.)
__device__ __forceinline__ void phase_a2_half(
    float* sm, __hip_bfloat16* hb, const float* xbuf, int tid, int tR0,
    int tC0, int rg_lo, int roff) {
  __hip_bfloat16* xsTh = hb + XSTH_H;
  for (int i = tid; i < 14 * 13; i += 256) {
    int rg = rg_lo + (i % 14);           // lane-consecutive row group
    int jj = i / 14;
    int rr0 = rg * 3;                    // xs rows rr0..rr0+2
    const float* rp = xbuf + (rr0 - roff) * XRAW_STR + jj * 4;
    float w[5][8];
    #pragma unroll
    for (int k = 0; k < 5; ++k) {
      float4 a = *(const float4*)(rp + k * XRAW_STR);
      float4 b = *(const float4*)(rp + k * XRAW_STR + 4);
      w[k][0] = a.x; w[k][1] = a.y; w[k][2] = a.z; w[k][3] = a.w;
      w[k][4] = b.x; w[k][5] = b.y; w[k][6] = b.z; w[k][7] = b.w;
    }
    int gc0 = tC0 + jj * 4 - 12;
    bool cv[7];
    #pragma unroll
    for (int p = 1; p <= 6; ++p) cv[p] = (unsigned)(gc0 + p) < 128u;

    #pragma unroll
    for (int k = 0; k < 3; ++k) {
      int rr = rr0 + k;
      int gr = tR0 + rr - 10;
      bool rv0 = (unsigned)(gr - 1) < 128u;
      bool rv1 = (unsigned)(gr) < 128u;
      bool rv2 = (unsigned)(gr + 1) < 128u;
      float M0[7], M1[7], M2[7];
      #pragma unroll
      for (int p = 1; p <= 6; ++p) {
        M0[p] = (rv0 && cv[p]) ? w[k][p] : -3.402823466e38f;
        M1[p] = (rv1 && cv[p]) ? w[k + 1][p] : -3.402823466e38f;
        M2[p] = (rv2 && cv[p]) ? w[k + 2][p] : -3.402823466e38f;
      }
      float uq[4];
      #pragma unroll
      for (int q = 0; q < 4; ++q) {
        float s = w[k][q + 1] + w[k][q + 2] + w[k][q + 3] + w[k + 1][q + 1] +
                  w[k + 1][q + 2] + w[k + 1][q + 3] + w[k + 2][q + 1] +
                  w[k + 2][q + 2] + w[k + 2][q + 3];
        float m = fmaxf(
            fmaxf(fmaxf(M0[q + 1], M0[q + 2]), fmaxf(M0[q + 3], M1[q + 1])),
            fmaxf(fmaxf(M1[q + 2], M1[q + 3]),
                  fmaxf(fmaxf(M2[q + 1], M2[q + 2]), M2[q + 3])));
        float val = w[k + 1][q + 2] + s * (1.f / 9.f) + m;
        bool vo = rv1 && ((unsigned)(gc0 + q + 2) < 128u);
        uq[q] = vo ? val : 0.f;
      }
      *(float4*)(sm + rr * XS_STR + jj * 4) =
          make_float4(uq[0], uq[1], uq[2], uq[3]);
      int rt = rr - 8;                   // xsTh row (tile row -2..65)
      if ((unsigned)rt < 68u) {
        #pragma unroll
        for (int q = 0; q < 4; ++q) {
          int ct = jj * 4 + q - 8;       // xsTh col (tile col -2..33)
          if ((unsigned)ct < 36u)
            xsTh[ct * 72 + rt] = __float2bfloat16(uq[q]);
        }
      }
    }
  }
}

__global__ __launch_bounds__(256, 4) void k_dwsum(
    const float* __restrict__ x, float* __restrict__ T,
    const float* __restrict__ w55, const float* __restrict__ b55,
    const float* __restrict__ w17_0, const float* __restrict__ b17_0,
    const float* __restrict__ w17_1, const float* __restrict__ b17_1,
    const float* __restrict__ w111_0, const float* __restrict__ b111_0,
    const float* __restrict__ w111_1, const float* __restrict__ b111_1,
    const float* __restrict__ w211_0, const float* __restrict__ b211_0,
    const float* __restrict__ w211_1, const float* __restrict__ b211_1) {
  __shared__ float sm[SMEM_FLOATS];
  __hip_bfloat16* hb = (__hip_bfloat16*)sm;

  const int bid = blockIdx.x;
  const int pl = bid >> 3;
  const int t = bid & 7;
  const int tR0 = (t >> 2) * 64;
  const int tC0 = (t & 3) * 32;
  const int ch = pl & (CC - 1);
  const float* xp = x + (size_t)pl * PLANE;
  float* Tp = T + (size_t)pl * TPSTR;
  const int tid = threadIdx.x;

  float* xbuf = sm + UNION_F;
  const int base_r = tR0 - 11, base_c = tC0 - 12;

  // ---- phase A pass 1: raw rows 0..43 of halo tile ----
  for (int i = tid; i < 44 * 14; i += 256) {
    int rr = i / 14;
    int jj = i - rr * 14;
    int gr = base_r + rr;
    int gc = base_c + jj * 4;
    float4 v = make_float4(0.f, 0.f, 0.f, 0.f);
    if ((unsigned)gr < 128u && (unsigned)gc < 128u)
      v = *(const float4*)(xp + gr * WW + gc);
    *(float4*)(xbuf + rr * XRAW_STR + jj * 4) = v;
  }
  __syncthreads();
  phase_a2_half(sm, hb, xbuf, tid, tR0, tC0, 0, 0);   // xs rows 0..41
  __syncthreads();
  // ---- phase A pass 2: raw rows 42..85 ----
  for (int i = tid; i < 44 * 14; i += 256) {
    int rr = i / 14;
    int jj = i - rr * 14;
    int gr = base_r + 42 + rr;
    int gc = base_c + jj * 4;
    float4 v = make_float4(0.f, 0.f, 0.f, 0.f);
    if ((unsigned)gr < 128u && (unsigned)gc < 128u)
      v = *(const float4*)(xp + gr * WW + gc);
    *(float4*)(xbuf + rr * XRAW_STR + jj * 4) = v;
  }
  __syncthreads();
  phase_a2_half(sm, hb, xbuf, tid, tR0, tC0, 14, 42); // xs rows 42..83

  float k7[7], k11[11], k21[21];
  #pragma unroll
  for (int i = 0; i < 7; ++i) k7[i] = w17_0[ch * 7 + i];
  #pragma unroll
  for (int i = 0; i < 11; ++i) k11[i] = w111_0[ch * 11 + i];
  #pragma unroll
  for (int i = 0; i < 21; ++i) k21[i] = w211_0[ch * 21 + i];
  float bb7 = 3.f * b17_0[ch];
  float bb11 = 3.f * b111_0[ch];
  float bb21 = 3.f * b211_0[ch];

  __syncthreads();

  // ---- phase B: horizontal convs; bf16 transposed stores (lane-consec rr) --
  for (int it = tid; it < 84 * 4; it += 256) {
    int rr = it % 84;
    int cg = it / 84;                    // output tile cols cg*8..+7
    float w[28];
    const float* xr = sm + rr * XS_STR + cg * 8;
    #pragma unroll
    for (int j = 0; j < 7; ++j) {
      float4 v = *(const float4*)(xr + 4 * j);
      w[4 * j] = v.x; w[4 * j + 1] = v.y; w[4 * j + 2] = v.z; w[4 * j + 3] = v.w;
    }
    int gr = tR0 + rr - 10;
    bool rv = (unsigned)gr < 128u;
    bool v11r = (rr >= 5) && (rr <= 78);
    bool v7r = (rr >= 7) && (rr <= 76);
    #pragma unroll
    for (int j = 0; j < 8; ++j) {
      float a21 = bb21, a11 = bb11, a7 = bb7;
      #pragma unroll
      for (int d = 0; d < 21; ++d) a21 += k21[d] * w[j + d];
      #pragma unroll
      for (int d = 0; d < 11; ++d) a11 += k11[d] * w[j + 5 + d];
      #pragma unroll
      for (int d = 0; d < 7; ++d) a7 += k7[d] * w[j + 7 + d];
      int c = cg * 8 + j;
      hb[H21_H + c * 88 + rr] = __float2bfloat16(rv ? a21 : 0.f);
      if (v11r) hb[H11_H + c * 88 + rr - 5] = __float2bfloat16(rv ? a11 : 0.f);
      if (v7r) hb[H7_H + c * 88 + rr - 7] = __float2bfloat16(rv ? a7 : 0.f);
    }
  }

  float v7a[7], v11a[11], v21a[21], w5a[25];
  #pragma unroll
  for (int i = 0; i < 7; ++i) v7a[i] = w17_1[ch * 7 + i];
  #pragma unroll
  for (int i = 0; i < 11; ++i) v11a[i] = w111_1[ch * 11 + i];
  #pragma unroll
  for (int i = 0; i < 21; ++i) v21a[i] = w211_1[ch * 21 + i];
  #pragma unroll
  for (int i = 0; i < 25; ++i) w5a[i] = w55[ch * 25 + i];
  float bsum = 3.f * (b55[ch] + b17_1[ch] + b111_1[ch] + b211_1[ch]);

  __syncthreads();

  // ---- phase C: vertical convs + 5x5; 8 rows/thread along a column ----
  {
    int c = tid & 31;
    int r0 = (tid >> 5) * 8;
    float acc[8];
    #pragma unroll
    for (int j = 0; j < 8; ++j) acc[j] = bsum;

    float A[28];
    {  // h21: indices r0..r0+27 (28 halves)
      const unsigned* p = (const unsigned*)&hb[H21_H + c * 88 + r0];
      uint4 q0 = *(const uint4*)p;
      uint4 q1 = *(const uint4*)(p + 4);
      uint4 q2 = *(const uint4*)(p + 8);
      uint2 q3 = *(const uint2*)(p + 12);
      A[0]=lo16(q0.x);A[1]=hi16(q0.x);A[2]=lo16(q0.y);A[3]=hi16(q0.y);
      A[4]=lo16(q0.z);A[5]=hi16(q0.z);A[6]=lo16(q0.w);A[7]=hi16(q0.w);
      A[8]=lo16(q1.x);A[9]=hi16(q1.x);A[10]=lo16(q1.y);A[11]=hi16(q1.y);
      A[12]=lo16(q1.z);A[13]=hi16(q1.z);A[14]=lo16(q1.w);A[15]=hi16(q1.w);
      A[16]=lo16(q2.x);A[17]=hi16(q2.x);A[18]=lo16(q2.y);A[19]=hi16(q2.y);
      A[20]=lo16(q2.z);A[21]=hi16(q2.z);A[22]=lo16(q2.w);A[23]=hi16(q2.w);
      A[24]=lo16(q3.x);A[25]=hi16(q3.x);A[26]=lo16(q3.y);A[27]=hi16(q3.y);
      #pragma unroll
      for (int d = 0; d < 21; ++d)
        #pragma unroll
        for (int j = 0; j < 8; ++j) acc[j] += v21a[d] * A[d + j];
    }
    {  // h11: indices r0..r0+17 (18 halves, read 20)
      const unsigned* p = (const unsigned*)&hb[H11_H + c * 88 + r0];
      uint4 q0 = *(const uint4*)p;
      uint4 q1 = *(const uint4*)(p + 4);
      uint2 q2 = *(const uint2*)(p + 8);
      A[0]=lo16(q0.x);A[1]=hi16(q0.x);A[2]=lo16(q0.y);A[3]=hi16(q0.y);
      A[4]=lo16(q0.z);A[5]=hi16(q0.z);A[6]=lo16(q0.w);A[7]=hi16(q0.w);
      A[8]=lo16(q1.x);A[9]=hi16(q1.x);A[10]=lo16(q1.y);A[11]=hi16(q1.y);
      A[12]=lo16(q1.z);A[13]=hi16(q1.z);A[14]=lo16(q1.w);A[15]=hi16(q1.w);
      A[16]=lo16(q2.x);A[17]=hi16(q2.x);
      #pragma unroll
      for (int d = 0; d < 11; ++d)
        #pragma unroll
        for (int j = 0; j < 8; ++j) acc[j] += v11a[d] * A[d + j];
    }
    {  // h7: indices r0..r0+13 (14 halves, read 16)
      const unsigned* p = (const unsigned*)&hb[H7_H + c * 88 + r0];
      uint4 q0 = *(const uint4*)p;
      uint4 q1 = *(const uint4*)(p + 4);
      A[0]=lo16(q0.x);A[1]=hi16(q0.x);A[2]=lo16(q0.y);A[3]=hi16(q0.y);
      A[4]=lo16(q0.z);A[5]=hi16(q0.z);A[6]=lo16(q0.w);A[7]=hi16(q0.w);
      A[8]=lo16(q1.x);A[9]=hi16(q1.x);A[10]=lo16(q1.y);A[11]=hi16(q1.y);
      A[12]=lo16(q1.z);A[13]=hi16(q1.z);
      #pragma unroll
      for (int d = 0; d < 7; ++d)
        #pragma unroll
        for (int j = 0; j < 8; ++j) acc[j] += v7a[d] * A[d + j];
    }
    {  // 5x5 from bf16 transposed U: cols c..c+4, rows r0..r0+11
      #pragma unroll
      for (int dc = 0; dc < 5; ++dc) {
        const unsigned* p = (const unsigned*)&hb[XSTH_H + (c + dc) * 72 + r0];
        uint4 q0 = *(const uint4*)p;
        uint2 q1 = *(const uint2*)(p + 4);
        float X[12];
        X[0]=lo16(q0.x);X[1]=hi16(q0.x);X[2]=lo16(q0.y);X[3]=hi16(q0.y);
        X[4]=lo16(q0.z);X[5]=hi16(q0.z);X[6]=lo16(q0.w);X[7]=hi16(q0.w);
        X[8]=lo16(q1.x);X[9]=hi16(q1.x);X[10]=lo16(q1.y);X[11]=hi16(q1.y);
        #pragma unroll
        for (int dr = 0; dr < 5; ++dr)
          #pragma unroll
          for (int j = 0; j < 8; ++j) acc[j] += w5a[dr * 5 + dc] * X[j + dr];
      }
    }
    #pragma unroll
    for (int j = 0; j < 8; ++j)
      Tp[(size_t)(tR0 + r0 + j) * WW + tC0 + c] = acc[j];
  }
}

// ---------------------------------------------------------------------------
// k_mix: out = (W11 . T + 3*b11) * x.  T has padded plane stride TPSTR.
// v6: EXACT v1 skeleton (3-slot register ring, 64 load-instrs/thread, no
// k-loop barriers, plain __launch_bounds__(256)) with the mapping changed
// 4px x 8co -> 2px x 16co:
//   - T redundancy per block 8x -> 4x (same instr count, float2 instead of
//     float4); tests whether v1 was HBM-bound on redundant T traffic.
//   - cog = tid>>6 = wave index -> all W LDS reads are wave-uniform
//     broadcasts.
// VGPR ~ 85 (acc 32 + ring 24 + misc) -> no spill risk.
// ---------------------------------------------------------------------------
__global__ __launch_bounds__(256) void k_mix(const float* __restrict__ T,
                                             const float* __restrict__ x,
                                             const float* __restrict__ w11,
                                             const float* __restrict__ b11,
                                             float* __restrict__ out) {
  __shared__ float Wt[64 * 68];            // [ci][co], stride 68
  int bid = blockIdx.x;
  int b = bid >> 7;
  int px0 = (bid & 127) * 128;
  int tid = threadIdx.x;

  for (int i = tid; i < 4096; i += 256) {
    int co = i >> 6, ci = i & 63;
    Wt[ci * 68 + co] = w11[i];
  }
  __syncthreads();

  int pxg = tid & 63;                      // 64 groups x 2 px
  int cog = tid >> 6;                      // 4 groups (waves) x 16 co
  const float* Tb = T + (size_t)b * 64 * TPSTR + px0 + pxg * 2;
  const float* wp = Wt + cog * 16;

  float acc[16][2];
  #pragma unroll
  for (int a = 0; a < 16; ++a) {
    acc[a][0] = 0.f;
    acc[a][1] = 0.f;
  }

  float2 tb[3][4];
  #pragma unroll
  for (int kk = 0; kk < 4; ++kk)
    tb[0][kk] = *(const float2*)(Tb + (size_t)kk * TPSTR);
  #pragma unroll
  for (int kk = 0; kk < 4; ++kk)
    tb[1][kk] = *(const float2*)(Tb + (size_t)(4 + kk) * TPSTR);

  #pragma unroll
  for (int kc = 0; kc < 16; ++kc) {
    const int cur = kc % 3;
    if (kc < 14) {
      const int nxt = (kc + 2) % 3;
      #pragma unroll
      for (int kk = 0; kk < 4; ++kk)
        tb[nxt][kk] =
            *(const float2*)(Tb + (size_t)((kc + 2) * 4 + kk) * TPSTR);
    }
    #pragma unroll
    for (int kk = 0; kk < 4; ++kk) {
      int k = kc * 4 + kk;
      const float* wr = wp + k * 68;       // wave-uniform -> LDS broadcast
      float2 tv = tb[cur][kk];
      #pragma unroll
      for (int g = 0; g < 4; ++g) {
        float4 qg = *(const float4*)(wr + g * 4);
        float wf4[4] = {qg.x, qg.y, qg.z, qg.w};
        #pragma unroll
        for (int a = 0; a < 4; ++a) {
          acc[g * 4 + a][0] += wf4[a] * tv.x;
          acc[g * 4 + a][1] += wf4[a] * tv.y;
        }
      }
    }
  }

  const float* xb = x + (size_t)b * (CC * PLANE) + px0 + pxg * 2;
  float* ob = out + (size_t)b * (CC * PLANE) + px0 + pxg * 2;
  #pragma unroll
  for (int a = 0; a < 16; ++a) {
    int co = cog * 16 + a;
    float bb = 3.f * b11[co];
    float2 xv = *(const float2*)(xb + (size_t)co * PLANE);
    float2 o;
    o.x = (acc[a][0] + bb) * xv.x;
    o.y = (acc[a][1] + bb) * xv.y;
    *(float2*)(ob + (size_t)co * PLANE) = o;
  }
}

extern "C" void kernel_launch(void* const* d_in, const int* in_sizes, int n_in,
                              void* d_out, int out_size, void* d_ws,
                              size_t ws_size, hipStream_t stream) {
  const float* x = (const float*)d_in[0];
  const float* w55 = (const float*)d_in[1];
  const float* b55 = (const float*)d_in[2];
  const float* w17_0 = (const float*)d_in[3];
  const float* b17_0 = (const float*)d_in[4];
  const float* w17_1 = (const float*)d_in[5];
  const float* b17_1 = (const float*)d_in[6];
  const float* w111_0 = (const float*)d_in[7];
  const float* b111_0 = (const float*)d_in[8];
  const float* w111_1 = (const float*)d_in[9];
  const float* b111_1 = (const float*)d_in[10];
  const float* w211_0 = (const float*)d_in[11];
  const float* b211_0 = (const float*)d_in[12];
  const float* w211_1 = (const float*)d_in[13];
  const float* b211_1 = (const float*)d_in[14];
  const float* w11 = (const float*)d_in[15];
  const float* b11 = (const float*)d_in[16];
  float* outp = (float*)d_out;

  float* T = (float*)d_ws;                 // [16*64][TPSTR]

  k_dwsum<<<BB * CC * 8, 256, 0, stream>>>(
      x, T, w55, b55, w17_0, b17_0, w17_1, b17_1, w111_0, b111_0, w111_1,
      b111_1, w211_0, b211_0, w211_1, b211_1);
  k_mix<<<BB * 128, 256, 0, stream>>>(T, x, w11, b11, outp);
}

// Round 7
// 283.029 us; speedup vs baseline: 2.5350x; 1.0062x over previous
//
#include <hip/hip_runtime.h>
#include <hip/hip_bf16.h>
#include <cstdint>

#define HH 128
#define WW 128
#define CC 64
#define BB 16
#define PLANE (HH*WW)
// T workspace layout v7: T3[b][row][ci][col]  ("[B][H][C][W]").
// A k_mix block (b,row) reads T3[b][row][*][*] = 64*128 floats = one
// CONTIGUOUS 32 KB stream (previous [plane][px] layout made each block read
// 64 x 512 B islands strided 66 KB apart -- the measured ~1.4 TB/s killer).
#define TROW   8192       // floats per (b,row): 64 ci * 128 col
#define TBATCH (128*TROW) // floats per batch

// k_dwsum LDS layout (two-pass xbuf -> 39552 B -> 4 blocks/CU).
//   xs   [84][52] f32  U row-major, rows -10..73, cols -10..41
//   xsTh [36][72] bf16 U col-major, cols -2..33, rows -2..65
//   h7T  [32][88] bf16 rows -3..66 (70 used)
//   union { xbuf [44][60] f32 (phase A, two passes: raw rows 0..43 / 42..85)
//         | h11T [32][88] bf16 ; h21T [32][88] bf16 }
#define XS_STR    52
#define XRAW_STR  60
#define XSTH_H    8736    // half-index of xsTh   (= 4368 floats * 2)
#define H7_H      11328   // half-index of h7T    (= 5664 floats * 2)
#define UNION_F   7072    // float-index of xbuf
#define H11_H     14144   // half-index of h11T   (inside union)
#define H21_H     16960   // half-index of h21T   (inside union)
#define SMEM_FLOATS 9888  // 39552 B -> 4 blocks/CU

__device__ __forceinline__ float lo16(unsigned int u) {
  return __uint_as_float(u << 16);
}
__device__ __forceinline__ float hi16(unsigned int u) {
  return __uint_as_float(u & 0xffff0000u);
}

// A2 half-pass: U = x + avg3 + max3 for rg in [rg_lo, rg_lo+14).
// xbuf holds raw rows [roff, roff+44) of the halo tile.
__device__ __forceinline__ void phase_a2_half(
    float* sm, __hip_bfloat16* hb, const float* xbuf, int tid, int tR0,
    int tC0, int rg_lo, int roff) {
  __hip_bfloat16* xsTh = hb + XSTH_H;
  for (int i = tid; i < 14 * 13; i += 256) {
    int rg = rg_lo + (i % 14);           // lane-consecutive row group
    int jj = i / 14;
    int rr0 = rg * 3;                    // xs rows rr0..rr0+2
    const float* rp = xbuf + (rr0 - roff) * XRAW_STR + jj * 4;
    float w[5][8];
    #pragma unroll
    for (int k = 0; k < 5; ++k) {
      float4 a = *(const float4*)(rp + k * XRAW_STR);
      float4 b = *(const float4*)(rp + k * XRAW_STR + 4);
      w[k][0] = a.x; w[k][1] = a.y; w[k][2] = a.z; w[k][3] = a.w;
      w[k][4] = b.x; w[k][5] = b.y; w[k][6] = b.z; w[k][7] = b.w;
    }
    int gc0 = tC0 + jj * 4 - 12;
    bool cv[7];
    #pragma unroll
    for (int p = 1; p <= 6; ++p) cv[p] = (unsigned)(gc0 + p) < 128u;

    #pragma unroll
    for (int k = 0; k < 3; ++k) {
      int rr = rr0 + k;
      int gr = tR0 + rr - 10;
      bool rv0 = (unsigned)(gr - 1) < 128u;
      bool rv1 = (unsigned)(gr) < 128u;
      bool rv2 = (unsigned)(gr + 1) < 128u;
      float M0[7], M1[7], M2[7];
      #pragma unroll
      for (int p = 1; p <= 6; ++p) {
        M0[p] = (rv0 && cv[p]) ? w[k][p] : -3.402823466e38f;
        M1[p] = (rv1 && cv[p]) ? w[k + 1][p] : -3.402823466e38f;
        M2[p] = (rv2 && cv[p]) ? w[k + 2][p] : -3.402823466e38f;
      }
      float uq[4];
      #pragma unroll
      for (int q = 0; q < 4; ++q) {
        float s = w[k][q + 1] + w[k][q + 2] + w[k][q + 3] + w[k + 1][q + 1] +
                  w[k + 1][q + 2] + w[k + 1][q + 3] + w[k + 2][q + 1] +
                  w[k + 2][q + 2] + w[k + 2][q + 3];
        float m = fmaxf(
            fmaxf(fmaxf(M0[q + 1], M0[q + 2]), fmaxf(M0[q + 3], M1[q + 1])),
            fmaxf(fmaxf(M1[q + 2], M1[q + 3]),
                  fmaxf(fmaxf(M2[q + 1], M2[q + 2]), M2[q + 3])));
        float val = w[k + 1][q + 2] + s * (1.f / 9.f) + m;
        bool vo = rv1 && ((unsigned)(gc0 + q + 2) < 128u);
        uq[q] = vo ? val : 0.f;
      }
      *(float4*)(sm + rr * XS_STR + jj * 4) =
          make_float4(uq[0], uq[1], uq[2], uq[3]);
      int rt = rr - 8;                   // xsTh row (tile row -2..65)
      if ((unsigned)rt < 68u) {
        #pragma unroll
        for (int q = 0; q < 4; ++q) {
          int ct = jj * 4 + q - 8;       // xsTh col (tile col -2..33)
          if ((unsigned)ct < 36u)
            xsTh[ct * 72 + rt] = __float2bfloat16(uq[q]);
        }
      }
    }
  }
}

__global__ __launch_bounds__(256, 4) void k_dwsum(
    const float* __restrict__ x, float* __restrict__ T,
    const float* __restrict__ w55, const float* __restrict__ b55,
    const float* __restrict__ w17_0, const float* __restrict__ b17_0,
    const float* __restrict__ w17_1, const float* __restrict__ b17_1,
    const float* __restrict__ w111_0, const float* __restrict__ b111_0,
    const float* __restrict__ w111_1, const float* __restrict__ b111_1,
    const float* __restrict__ w211_0, const float* __restrict__ b211_0,
    const float* __restrict__ w211_1, const float* __restrict__ b211_1) {
  __shared__ float sm[SMEM_FLOATS];
  __hip_bfloat16* hb = (__hip_bfloat16*)sm;

  const int bid = blockIdx.x;
  const int pl = bid >> 3;
  const int t = bid & 7;
  const int tR0 = (t >> 2) * 64;
  const int tC0 = (t & 3) * 32;
  const int ch = pl & (CC - 1);
  const int bb2 = pl >> 6;               // batch index
  const float* xp = x + (size_t)pl * PLANE;
  // T3[b][row][ch][col]: base for this (b, ch)
  float* Tp = T + (size_t)bb2 * TBATCH + (size_t)ch * 128;
  const int tid = threadIdx.x;

  float* xbuf = sm + UNION_F;
  const int base_r = tR0 - 11, base_c = tC0 - 12;

  // ---- phase A pass 1: raw rows 0..43 of halo tile ----
  for (int i = tid; i < 44 * 14; i += 256) {
    int rr = i / 14;
    int jj = i - rr * 14;
    int gr = base_r + rr;
    int gc = base_c + jj * 4;
    float4 v = make_float4(0.f, 0.f, 0.f, 0.f);
    if ((unsigned)gr < 128u && (unsigned)gc < 128u)
      v = *(const float4*)(xp + gr * WW + gc);
    *(float4*)(xbuf + rr * XRAW_STR + jj * 4) = v;
  }
  __syncthreads();
  phase_a2_half(sm, hb, xbuf, tid, tR0, tC0, 0, 0);   // xs rows 0..41
  __syncthreads();
  // ---- phase A pass 2: raw rows 42..85 ----
  for (int i = tid; i < 44 * 14; i += 256) {
    int rr = i / 14;
    int jj = i - rr * 14;
    int gr = base_r + 42 + rr;
    int gc = base_c + jj * 4;
    float4 v = make_float4(0.f, 0.f, 0.f, 0.f);
    if ((unsigned)gr < 128u && (unsigned)gc < 128u)
      v = *(const float4*)(xp + gr * WW + gc);
    *(float4*)(xbuf + rr * XRAW_STR + jj * 4) = v;
  }
  __syncthreads();
  phase_a2_half(sm, hb, xbuf, tid, tR0, tC0, 14, 42); // xs rows 42..83

  float k7[7], k11[11], k21[21];
  #pragma unroll
  for (int i = 0; i < 7; ++i) k7[i] = w17_0[ch * 7 + i];
  #pragma unroll
  for (int i = 0; i < 11; ++i) k11[i] = w111_0[ch * 11 + i];
  #pragma unroll
  for (int i = 0; i < 21; ++i) k21[i] = w211_0[ch * 21 + i];
  float bb7 = 3.f * b17_0[ch];
  float bb11 = 3.f * b111_0[ch];
  float bb21 = 3.f * b211_0[ch];

  __syncthreads();

  // ---- phase B: horizontal convs; bf16 transposed stores (lane-consec rr) --
  for (int it = tid; it < 84 * 4; it += 256) {
    int rr = it % 84;
    int cg = it / 84;                    // output tile cols cg*8..+7
    float w[28];
    const float* xr = sm + rr * XS_STR + cg * 8;
    #pragma unroll
    for (int j = 0; j < 7; ++j) {
      float4 v = *(const float4*)(xr + 4 * j);
      w[4 * j] = v.x; w[4 * j + 1] = v.y; w[4 * j + 2] = v.z; w[4 * j + 3] = v.w;
    }
    int gr = tR0 + rr - 10;
    bool rv = (unsigned)gr < 128u;
    bool v11r = (rr >= 5) && (rr <= 78);
    bool v7r = (rr >= 7) && (rr <= 76);
    #pragma unroll
    for (int j = 0; j < 8; ++j) {
      float a21 = bb21, a11 = bb11, a7 = bb7;
      #pragma unroll
      for (int d = 0; d < 21; ++d) a21 += k21[d] * w[j + d];
      #pragma unroll
      for (int d = 0; d < 11; ++d) a11 += k11[d] * w[j + 5 + d];
      #pragma unroll
      for (int d = 0; d < 7; ++d) a7 += k7[d] * w[j + 7 + d];
      int c = cg * 8 + j;
      hb[H21_H + c * 88 + rr] = __float2bfloat16(rv ? a21 : 0.f);
      if (v11r) hb[H11_H + c * 88 + rr - 5] = __float2bfloat16(rv ? a11 : 0.f);
      if (v7r) hb[H7_H + c * 88 + rr - 7] = __float2bfloat16(rv ? a7 : 0.f);
    }
  }

  float v7a[7], v11a[11], v21a[21], w5a[25];
  #pragma unroll
  for (int i = 0; i < 7; ++i) v7a[i] = w17_1[ch * 7 + i];
  #pragma unroll
  for (int i = 0; i < 11; ++i) v11a[i] = w111_1[ch * 11 + i];
  #pragma unroll
  for (int i = 0; i < 21; ++i) v21a[i] = w211_1[ch * 21 + i];
  #pragma unroll
  for (int i = 0; i < 25; ++i) w5a[i] = w55[ch * 25 + i];
  float bsum = 3.f * (b55[ch] + b17_1[ch] + b111_1[ch] + b211_1[ch]);

  __syncthreads();

  // ---- phase C: vertical convs + 5x5; 8 rows/thread along a column ----
  {
    int c = tid & 31;
    int r0 = (tid >> 5) * 8;
    float acc[8];
    #pragma unroll
    for (int j = 0; j < 8; ++j) acc[j] = bsum;

    float A[28];
    {  // h21: indices r0..r0+27 (28 halves)
      const unsigned* p = (const unsigned*)&hb[H21_H + c * 88 + r0];
      uint4 q0 = *(const uint4*)p;
      uint4 q1 = *(const uint4*)(p + 4);
      uint4 q2 = *(const uint4*)(p + 8);
      uint2 q3 = *(const uint2*)(p + 12);
      A[0]=lo16(q0.x);A[1]=hi16(q0.x);A[2]=lo16(q0.y);A[3]=hi16(q0.y);
      A[4]=lo16(q0.z);A[5]=hi16(q0.z);A[6]=lo16(q0.w);A[7]=hi16(q0.w);
      A[8]=lo16(q1.x);A[9]=hi16(q1.x);A[10]=lo16(q1.y);A[11]=hi16(q1.y);
      A[12]=lo16(q1.z);A[13]=hi16(q1.z);A[14]=lo16(q1.w);A[15]=hi16(q1.w);
      A[16]=lo16(q2.x);A[17]=hi16(q2.x);A[18]=lo16(q2.y);A[19]=hi16(q2.y);
      A[20]=lo16(q2.z);A[21]=hi16(q2.z);A[22]=lo16(q2.w);A[23]=hi16(q2.w);
      A[24]=lo16(q3.x);A[25]=hi16(q3.x);A[26]=lo16(q3.y);A[27]=hi16(q3.y);
      #pragma unroll
      for (int d = 0; d < 21; ++d)
        #pragma unroll
        for (int j = 0; j < 8; ++j) acc[j] += v21a[d] * A[d + j];
    }
    {  // h11: indices r0..r0+17 (18 halves, read 20)
      const unsigned* p = (const unsigned*)&hb[H11_H + c * 88 + r0];
      uint4 q0 = *(const uint4*)p;
      uint4 q1 = *(const uint4*)(p + 4);
      uint2 q2 = *(const uint2*)(p + 8);
      A[0]=lo16(q0.x);A[1]=hi16(q0.x);A[2]=lo16(q0.y);A[3]=hi16(q0.y);
      A[4]=lo16(q0.z);A[5]=hi16(q0.z);A[6]=lo16(q0.w);A[7]=hi16(q0.w);
      A[8]=lo16(q1.x);A[9]=hi16(q1.x);A[10]=lo16(q1.y);A[11]=hi16(q1.y);
      A[12]=lo16(q1.z);A[13]=hi16(q1.z);A[14]=lo16(q1.w);A[15]=hi16(q1.w);
      A[16]=lo16(q2.x);A[17]=hi16(q2.x);
      #pragma unroll
      for (int d = 0; d < 11; ++d)
        #pragma unroll
        for (int j = 0; j < 8; ++j) acc[j] += v11a[d] * A[d + j];
    }
    {  // h7: indices r0..r0+13 (14 halves, read 16)
      const unsigned* p = (const unsigned*)&hb[H7_H + c * 88 + r0];
      uint4 q0 = *(const uint4*)p;
      uint4 q1 = *(const uint4*)(p + 4);
      A[0]=lo16(q0.x);A[1]=hi16(q0.x);A[2]=lo16(q0.y);A[3]=hi16(q0.y);
      A[4]=lo16(q0.z);A[5]=hi16(q0.z);A[6]=lo16(q0.w);A[7]=hi16(q0.w);
      A[8]=lo16(q1.x);A[9]=hi16(q1.x);A[10]=lo16(q1.y);A[11]=hi16(q1.y);
      A[12]=lo16(q1.z);A[13]=hi16(q1.z);
      #pragma unroll
      for (int d = 0; d < 7; ++d)
        #pragma unroll
        for (int j = 0; j < 8; ++j) acc[j] += v7a[d] * A[d + j];
    }
    {  // 5x5 from bf16 transposed U: cols c..c+4, rows r0..r0+11
      #pragma unroll
      for (int dc = 0; dc < 5; ++dc) {
        const unsigned* p = (const unsigned*)&hb[XSTH_H + (c + dc) * 72 + r0];
        uint4 q0 = *(const uint4*)p;
        uint2 q1 = *(const uint2*)(p + 4);
        float X[12];
        X[0]=lo16(q0.x);X[1]=hi16(q0.x);X[2]=lo16(q0.y);X[3]=hi16(q0.y);
        X[4]=lo16(q0.z);X[5]=hi16(q0.z);X[6]=lo16(q0.w);X[7]=hi16(q0.w);
        X[8]=lo16(q1.x);X[9]=hi16(q1.x);X[10]=lo16(q1.y);X[11]=hi16(q1.y);
        #pragma unroll
        for (int dr = 0; dr < 5; ++dr)
          #pragma unroll
          for (int j = 0; j < 8; ++j) acc[j] += w5a[dr * 5 + dc] * X[j + dr];
      }
    }
    // T3[b][row][ch][col]: same 128 B-contiguous wave stores as before
    // (32 lanes x 4 B, c consecutive), only chunk placement changed.
    #pragma unroll
    for (int j = 0; j < 8; ++j)
      Tp[(size_t)(tR0 + r0 + j) * TROW + tC0 + c] = acc[j];
  }
}

// ---------------------------------------------------------------------------
// k_mix: out = (W11 . T + 3*b11) * x.  v7 = EXACT v1 skeleton (128 px x 64 co
// per block, 4 px x 8 co per thread, 3-slot register prefetch ring, no k-loop
// barriers, plain __launch_bounds__(256)), but T is now T3[b][row][ci][col]:
// the block's entire T tile (64 ci x 128 col) is ONE contiguous 32 KB stream
// (ci stride = 512 B). The 8 co-groups' re-reads hit a hot 32 KB L1/L2
// window instead of missing across a 4.2 MB span.
// ---------------------------------------------------------------------------
__global__ __launch_bounds__(256) void k_mix(const float* __restrict__ T,
                                             const float* __restrict__ x,
                                             const float* __restrict__ w11,
                                             const float* __restrict__ b11,
                                             float* __restrict__ out) {
  __shared__ float Wt[64 * 68];            // [ci][co], stride 68
  int bid = blockIdx.x;
  int b = bid >> 7;
  int row = bid & 127;
  int px0 = row * 128;
  int tid = threadIdx.x;

  for (int i = tid; i < 4096; i += 256) {
    int co = i >> 6, ci = i & 63;
    Wt[ci * 68 + co] = w11[i];
  }
  __syncthreads();

  int pxg = tid & 31;                      // 32 groups x 4 px
  int cog = tid >> 5;                      // 8 groups x 8 co
  // contiguous tile: T3[b][row][ci][col], ci stride = 128 floats
  const float* Tb = T + (size_t)b * TBATCH + (size_t)row * TROW + pxg * 4;
  const float* wp = Wt + cog * 8;

  float acc[8][4];
  #pragma unroll
  for (int a = 0; a < 8; ++a)
    #pragma unroll
    for (int p = 0; p < 4; ++p) acc[a][p] = 0.f;

  float4 tb[3][4];
  #pragma unroll
  for (int kk = 0; kk < 4; ++kk)
    tb[0][kk] = *(const float4*)(Tb + (size_t)kk * 128);
  #pragma unroll
  for (int kk = 0; kk < 4; ++kk)
    tb[1][kk] = *(const float4*)(Tb + (size_t)(4 + kk) * 128);

  #pragma unroll
  for (int kc = 0; kc < 16; ++kc) {
    const int cur = kc % 3;
    if (kc < 14) {
      const int nxt = (kc + 2) % 3;
      #pragma unroll
      for (int kk = 0; kk < 4; ++kk)
        tb[nxt][kk] =
            *(const float4*)(Tb + (size_t)((kc + 2) * 4 + kk) * 128);
    }
    #pragma unroll
    for (int kk = 0; kk < 4; ++kk) {
      int k = kc * 4 + kk;
      float4 q0 = *(const float4*)(wp + k * 68);
      float4 q1 = *(const float4*)(wp + k * 68 + 4);
      float wf[8] = {q0.x, q0.y, q0.z, q0.w, q1.x, q1.y, q1.z, q1.w};
      float4 tv = tb[cur][kk];
      float tvv[4] = {tv.x, tv.y, tv.z, tv.w};
      #pragma unroll
      for (int a = 0; a < 8; ++a)
        #pragma unroll
        for (int p = 0; p < 4; ++p) acc[a][p] += wf[a] * tvv[p];
    }
  }

  const float* xb = x + (size_t)b * (CC * PLANE) + px0 + pxg * 4;
  float* ob = out + (size_t)b * (CC * PLANE) + px0 + pxg * 4;
  #pragma unroll
  for (int a = 0; a < 8; ++a) {
    int co = cog * 8 + a;
    float bb = 3.f * b11[co];
    float4 xv = *(const float4*)(xb + (size_t)co * PLANE);
    float4 o;
    o.x = (acc[a][0] + bb) * xv.x;
    o.y = (acc[a][1] + bb) * xv.y;
    o.z = (acc[a][2] + bb) * xv.z;
    o.w = (acc[a][3] + bb) * xv.w;
    *(float4*)(ob + (size_t)co * PLANE) = o;
  }
}

extern "C" void kernel_launch(void* const* d_in, const int* in_sizes, int n_in,
                              void* d_out, int out_size, void* d_ws,
                              size_t ws_size, hipStream_t stream) {
  const float* x = (const float*)d_in[0];
  const float* w55 = (const float*)d_in[1];
  const float* b55 = (const float*)d_in[2];
  const float* w17_0 = (const float*)d_in[3];
  const float* b17_0 = (const float*)d_in[4];
  const float* w17_1 = (const float*)d_in[5];
  const float* b17_1 = (const float*)d_in[6];
  const float* w111_0 = (const float*)d_in[7];
  const float* b111_0 = (const float*)d_in[8];
  const float* w111_1 = (const float*)d_in[9];
  const float* b111_1 = (const float*)d_in[10];
  const float* w211_0 = (const float*)d_in[11];
  const float* b211_0 = (const float*)d_in[12];
  const float* w211_1 = (const float*)d_in[13];
  const float* b211_1 = (const float*)d_in[14];
  const float* w11 = (const float*)d_in[15];
  const float* b11 = (const float*)d_in[16];
  float* outp = (float*)d_out;

  float* T = (float*)d_ws;                 // T3[16][128][64][128] = 64 MB

  k_dwsum<<<BB * CC * 8, 256, 0, stream>>>(
      x, T, w55, b55, w17_0, b17_0, w17_1, b17_1, w111_0, b111_0, w111_1,
      b111_1, w211_0, b211_0, w211_1, b211_1);
  k_mix<<<BB * 128, 256, 0, stream>>>(T, x, w11, b11, outp);
}